// Round 6
// baseline (158.481 us; speedup 1.0000x reference)
//
#include <hip/hip_runtime.h>
#include <cstdint>

// =====================================================================
// MultiHeadAttention_84576495993495  (round 6)
//
// Algebraic collapse: einsum('bhqk,bhvo->bhvo', attn, v) sums attn over
// BOTH q and k; softmax rows sum to 1 -> factor is exactly S=2048.
//   final = x @ (2048*Wp@Wv)^T + (2048*Wp@bv + bp)
// Wq/bq/Wk/bk unused.
//
// R6 changes (R5 counters: gemm2 44us with MfmaUtil 13 / VALU 11 / HBM 16
// / Occ 14 -- latency-bound at 2 blocks/CU with a long critical path):
//   - BM=64 x BN=128 tiles -> gemm2 grid 1024 = 4 blocks/CU (16 waves/CU),
//     LDS 24KB, __launch_bounds__(256,4).
//   - A (f32) register-prefetch: tile t+1's A loads issue during tile t's
//     staging; after the barrier only cvt+ds_write (reg-resident) is on
//     the critical path. Keeps R5's zero-copy A (no bf16 x in HBM).
// =====================================================================

typedef unsigned short u16;
typedef __bf16 bf16x8 __attribute__((ext_vector_type(8)));
typedef unsigned short u16x8 __attribute__((ext_vector_type(8)));
typedef float f32x4 __attribute__((ext_vector_type(4)));

__device__ __forceinline__ u16 f2bf(float f) {
  // round-to-nearest-even f32 -> bf16 bits (finite inputs)
  unsigned int u = __float_as_uint(f);
  u += 0x7fffu + ((u >> 16) & 1u);
  return (u16)(u >> 16);
}

// async global->LDS 16B copy; LDS dest = wave-uniform base + lane*16
__device__ __forceinline__ void load16(const void* g, void* l) {
  auto gp = (const __attribute__((address_space(1))) unsigned int*)(uintptr_t)g;
  auto lp = (__attribute__((address_space(3))) unsigned int*)(unsigned int)(uintptr_t)l;
  __builtin_amdgcn_global_load_lds(gp, lp, 16, 0, 0);
}

// ---------------------------------------------------------------------
// Prep: [0,1024) transpose+conv Wv -> Wv^T bf16 ; [1024,1280) bias fold
__global__ void k_prep(const float* __restrict__ Wv, const float* __restrict__ bv,
                       const float* __restrict__ Wp, const float* __restrict__ bp,
                       u16* __restrict__ wvtb, float* __restrict__ cv) {
  __shared__ float tile[32][33];
  const int b = blockIdx.x;
  const int tid = threadIdx.x;
  if (b < 1024) {  // transpose Wv (32x32 tiles)
    const int bi = (b & 31) * 32;   // output row block (i)
    const int bj = (b >> 5) * 32;   // output col block (j) = src row block
    const int tx = tid & 31;
    const int ty = tid >> 5;  // 0..7
    for (int r = ty; r < 32; r += 8)
      tile[r][tx] = Wv[(long)(bj + r) * 1024 + bi + tx];
    __syncthreads();
    for (int r = ty; r < 32; r += 8)
      wvtb[(long)(bi + r) * 1024 + bj + tx] = f2bf(tile[tx][r]);
  } else {  // cv[n] = 2048*dot(Wp[n,:],bv) + bp[n]
    const int row = (b - 1024) * 4 + (tid >> 6);
    const int lane = tid & 63;
    const float* w = Wp + (long)row * 1024;
    float s = 0.f;
    for (int j = lane; j < 1024; j += 64) s += w[j] * bv[j];
    for (int off = 32; off; off >>= 1) s += __shfl_down(s, off, 64);
    if (lane == 0) cv[row] = 2048.f * s + bp[row];
  }
}

// ---------------------------------------------------------------------
// reduce 4 split-K fp32 partial slabs -> bf16, *2048
__global__ void k_reduce(const float* __restrict__ p, u16* __restrict__ dst) {
  const long i = (long)(blockIdx.x * 256 + threadIdx.x) * 4;
  const float4 a = *(const float4*)(p + i);
  const float4 b = *(const float4*)(p + 1048576 + i);
  const float4 c = *(const float4*)(p + 2097152 + i);
  const float4 d = *(const float4*)(p + 3145728 + i);
  ushort4 o;
  o.x = f2bf((a.x + b.x + c.x + d.x) * 2048.f);
  o.y = f2bf((a.y + b.y + c.y + d.y) * 2048.f);
  o.z = f2bf((a.z + b.z + c.z + d.z) * 2048.f);
  o.w = f2bf((a.w + b.w + c.w + d.w) * 2048.f);
  *(ushort4*)(dst + i) = o;
}

// ---------------------------------------------------------------------
// NT GEMM: Out[M,N] (+bias) = bf16(A_f32[M,K]) @ B_bf16[N,K]^T
// BM=64, BN=128, BK=64. 256 threads = 4 waves side by side in N; each
// wave computes 64x32 (acc 4x2), 2 k-halves per K-iter.
// A f32 register-prefetched one tile ahead; cvt+ds_write_b128 after the
// barrier touches only registers. B staged via global_load_lds.
// LDS XOR-swizzled: 16B chunk kc of row r lives at slot kc ^ (r&7).
// MODE 0: fp32 out + bias, XCD-swizzled 1-D grid. MODE 1: split-K slab.
template <int MODE>
__global__ __launch_bounds__(256, 4) void k_gemm(
    const float* __restrict__ A, const u16* __restrict__ B, float* __restrict__ Out,
    const float* __restrict__ bias, int M, int N, int K) {
  __shared__ u16 As[64 * 64];    //  8 KB
  __shared__ u16 Bs[128 * 64];   // 16 KB

  const int tid = threadIdx.x;
  const int lane = tid & 63;
  const int wv = tid >> 6;
  const int waveN = wv << 5;     // 0/32/64/96
  const int l15 = lane & 15;
  const int quad = lane >> 4;

  long bm, bn;
  int kBeg, kEnd;
  if constexpr (MODE == 0) {
    // XCD swizzle: xcd = id%8 owns contiguous m-panels; the N/128 n-blocks
    // of one panel are temporally adjacent (A panel L2-resident).
    const int id = blockIdx.x;            // gridDim.x = (M/64)*(N/128)
    const int xcd = id & 7;
    const int j = id >> 3;
    const int nb = N >> 7;                // n-blocks per panel
    const int mPerXcd = M / 64 / 8;
    bm = (long)(xcd * mPerXcd + j / nb) * 64;
    bn = (long)(j % nb) * 128;
    kBeg = 0; kEnd = K;
  } else {
    bm = (long)blockIdx.x * 64;
    bn = (long)blockIdx.y * 128;
    const int kChunk = K / gridDim.z;
    kBeg = blockIdx.z * kChunk;
    kEnd = kBeg + kChunk;
  }

  // A map: thread handles row ar = tid>>2, 16 f32 at col (tid&3)*16
  const int ar = tid >> 2;
  const int acg = tid & 3;
  const float* Ap = A + (bm + ar) * (long)K + acg * 16;
  const int x0 = (acg * 2) ^ (ar & 7);        // swizzled chunk slots
  u16* Aw0 = As + ar * 64 + x0 * 8;
  u16* Aw1 = As + ar * 64 + (x0 ^ 1) * 8;

  // B map (global_load_lds): row = r*32 + tid>>3, slot tid&7, kc = slot^(row&7)
  const int srow = tid >> 3;
  const int sslot = tid & 7;

  const f32x4 zero = {0.f, 0.f, 0.f, 0.f};
  f32x4 acc[4][2];
#pragma unroll
  for (int i = 0; i < 4; ++i)
#pragma unroll
    for (int j = 0; j < 2; ++j) acc[i][j] = zero;

  // prologue: prefetch tile 0's A into registers
  float4 Ar0, Ar1, Ar2, Ar3;
  {
    const float4* ap = (const float4*)(Ap + kBeg);
    Ar0 = ap[0]; Ar1 = ap[1]; Ar2 = ap[2]; Ar3 = ap[3];
  }

  for (int k0 = kBeg; k0 < kEnd; k0 += 64) {
    __syncthreads();  // previous tile fully consumed
    // B: 128 rows x 64 k via async copy (issue first: starts HBM fetch)
#pragma unroll
    for (int r = 0; r < 4; ++r) {
      const int row = r * 32 + srow;
      const int kc = sslot ^ (row & 7);
      load16(B + (bn + row) * K + k0 + kc * 8, Bs + r * 2048 + wv * 512);
    }
    // A: cvt prefetched regs -> swizzled LDS (register-resident, short path)
    {
      u16x8 c0, c1;
      c0[0] = f2bf(Ar0.x); c0[1] = f2bf(Ar0.y); c0[2] = f2bf(Ar0.z); c0[3] = f2bf(Ar0.w);
      c0[4] = f2bf(Ar1.x); c0[5] = f2bf(Ar1.y); c0[6] = f2bf(Ar1.z); c0[7] = f2bf(Ar1.w);
      c1[0] = f2bf(Ar2.x); c1[1] = f2bf(Ar2.y); c1[2] = f2bf(Ar2.z); c1[3] = f2bf(Ar2.w);
      c1[4] = f2bf(Ar3.x); c1[5] = f2bf(Ar3.y); c1[6] = f2bf(Ar3.z); c1[7] = f2bf(Ar3.w);
      *(u16x8*)Aw0 = c0;
      *(u16x8*)Aw1 = c1;
    }
    // prefetch next tile's A (latency overlaps B drain + compute)
    if (k0 + 64 < kEnd) {
      const float4* ap = (const float4*)(Ap + k0 + 64);
      Ar0 = ap[0]; Ar1 = ap[1]; Ar2 = ap[2]; Ar3 = ap[3];
    }
    __syncthreads();  // staging drained

#pragma unroll
    for (int h = 0; h < 2; ++h) {
      bf16x8 af[4], bg[2];
#pragma unroll
      for (int t = 0; t < 4; ++t) {
        const int xk = ((h << 2) + quad) ^ (l15 & 7);   // swizzled chunk
        af[t] = *(const bf16x8*)(As + (t * 16 + l15) * 64 + xk * 8);
      }
#pragma unroll
      for (int t = 0; t < 2; ++t) {
        const int xk = ((h << 2) + quad) ^ (l15 & 7);
        bg[t] = *(const bf16x8*)(Bs + (waveN + t * 16 + l15) * 64 + xk * 8);
      }
#pragma unroll
      for (int i = 0; i < 4; ++i)
#pragma unroll
        for (int j = 0; j < 2; ++j)
          acc[i][j] = __builtin_amdgcn_mfma_f32_16x16x32_bf16(af[i], bg[j], acc[i][j], 0, 0, 0);
    }
  }

  // epilogue: C/D layout col = lane&15, row = quad*4 + reg  [m89/m91]
  float* outp = (MODE == 1) ? Out + (long)blockIdx.z * M * N : Out;
#pragma unroll
  for (int i = 0; i < 4; ++i) {
    const long gm = bm + i * 16 + quad * 4;
#pragma unroll
    for (int j = 0; j < 2; ++j) {
      const long gn = bn + waveN + j * 16 + l15;
      const float bb = (MODE == 0) ? bias[gn] : 0.f;
#pragma unroll
      for (int r = 0; r < 4; ++r)
        outp[(gm + r) * N + gn] = acc[i][j][r] + bb;
    }
  }
}

// =====================================================================
extern "C" void kernel_launch(void* const* d_in, const int* in_sizes, int n_in,
                              void* d_out, int out_size, void* d_ws, size_t ws_size,
                              hipStream_t stream) {
  // setup_inputs order: x, Wq, bq, Wk, bk, Wv, bv, Wp, bp
  const float* x  = (const float*)d_in[0];
  const float* Wv = (const float*)d_in[5];
  const float* bv = (const float*)d_in[6];
  const float* Wp = (const float*)d_in[7];
  const float* bp = (const float*)d_in[8];

  char* ws = (char*)d_ws;
  u16* wvtb  = (u16*)(ws);                      //  2 MB  Wv^T bf16
  u16* m2b   = (u16*)(ws + (2u << 20));         //  2 MB  M2 bf16
  float* cv  = (float*)(ws + (4u << 20));       //  4 KB  folded bias
  float* m2f = (float*)(ws + (4u << 20) + 4096);   // 16 MB split-K partials

  // 1) prep: transpose Wv + bias fold (x and Wp consumed as f32 by GEMMs)
  k_prep<<<1280, 256, 0, stream>>>(Wv, bv, Wp, bp, wvtb, cv);

  // 2) M2 partials = Wp @ Wv  (split-K=4: 16x8x4 = 512 blocks, 2/CU)
  k_gemm<1><<<dim3(16, 8, 4), 256, 0, stream>>>(Wp, wvtb, m2f, nullptr,
                                                1024, 1024, 1024);
  // 3) M2 = bf16(2048 * sum of partials)
  k_reduce<<<1024, 256, 0, stream>>>(m2f, m2b);

  // 4) out = x @ M2^T + cv  (128 m-panels x 8 n-blocks = 1024, 4/CU)
  k_gemm<0><<<1024, 256, 0, stream>>>(x, m2b, (float*)d_out, cv,
                                      8192, 1024, 1024);
}

// Round 7
// 140.723 us; speedup vs baseline: 1.1262x; 1.1262x over previous
//
#include <hip/hip_runtime.h>
#include <cstdint>

// =====================================================================
// MultiHeadAttention_84576495993495  (round 7)
//
// Algebraic collapse: einsum('bhqk,bhvo->bhvo', attn, v) sums attn over
// BOTH q and k; softmax rows sum to 1 -> factor is exactly S=2048.
//   final = x @ (2048*Wp@Wv)^T + (2048*Wp@bv + bp)
// Wq/bq/Wk/bk unused.
//
// R7 (R5/R6 counters: MfmaUtil 12%, latency-bound -- per-iter vmcnt(0)
// drain ~300-900cyc vs only 77cyc of MFMA):
//   - BK=128 with BM=BN=128: 64 MFMA/wave/iter (307 cyc) per drain, 8
//     iters. LDS 64KB -> 2 blocks/CU. Amortize the barrier drain.
//   - Revert to pre-converted bf16 x (R4 style): no f32/cvt in the GEMM.
//   - XCD-grouped dispatch: one A-panel's 8 n-blocks adjacent on one XCD
//     (panel 256KB + B 2MB fit per-XCD L2).
//   - gemm1 = same kernel, split-K=4 (grid 8x8x4), reduce applies *2048.
// =====================================================================

typedef unsigned short u16;
typedef __bf16 bf16x8 __attribute__((ext_vector_type(8)));
typedef float f32x4 __attribute__((ext_vector_type(4)));

__device__ __forceinline__ u16 f2bf(float f) {
  // round-to-nearest-even f32 -> bf16 bits (finite inputs)
  unsigned int u = __float_as_uint(f);
  u += 0x7fffu + ((u >> 16) & 1u);
  return (u16)(u >> 16);
}

// async global->LDS 16B copy; LDS dest = wave-uniform base + lane*16
__device__ __forceinline__ void load16(const void* g, void* l) {
  auto gp = (const __attribute__((address_space(1))) unsigned int*)(uintptr_t)g;
  auto lp = (__attribute__((address_space(3))) unsigned int*)(unsigned int)(uintptr_t)l;
  __builtin_amdgcn_global_load_lds(gp, lp, 16, 0, 0);
}

// ---------------------------------------------------------------------
// Fused prep. Block ranges:
//   [0,8192)      conv x   f32->bf16 (4 elem/thread)
//   [8192,9216)   conv Wp  f32->bf16
//   [9216,10240)  transpose+conv Wv -> Wv^T bf16 (32x32 tiles)
//   [10240,10496) cv[n] = 2048*dot(Wp[n,:],bv) + bp[n]
__global__ void k_prep(const float* __restrict__ x, const float* __restrict__ Wv,
                       const float* __restrict__ bv, const float* __restrict__ Wp,
                       const float* __restrict__ bp, u16* __restrict__ xb,
                       u16* __restrict__ wpb, u16* __restrict__ wvtb,
                       float* __restrict__ cv) {
  __shared__ float tile[32][33];
  const int b = blockIdx.x;
  const int tid = threadIdx.x;
  if (b < 9216) {  // conversions
    const float* src = (b < 8192) ? x : Wp;
    u16* dst = (b < 8192) ? xb : wpb;
    const long base = (long)((b < 8192) ? b : (b - 8192)) * 1024 + tid * 4;
    const float4 v = *(const float4*)(src + base);
    ushort4 o;
    o.x = f2bf(v.x); o.y = f2bf(v.y); o.z = f2bf(v.z); o.w = f2bf(v.w);
    *(ushort4*)(dst + base) = o;
  } else if (b < 10240) {  // transpose Wv
    const int tb = b - 9216;
    const int bi = (tb & 31) * 32;   // output row block (i)
    const int bj = (tb >> 5) * 32;   // output col block (j) = src row block
    const int tx = tid & 31;
    const int ty = tid >> 5;  // 0..7
    for (int r = ty; r < 32; r += 8)
      tile[r][tx] = Wv[(long)(bj + r) * 1024 + bi + tx];
    __syncthreads();
    for (int r = ty; r < 32; r += 8)
      wvtb[(long)(bi + r) * 1024 + bj + tx] = f2bf(tile[tx][r]);
  } else {  // bias fold
    const int row = (b - 10240) * 4 + (tid >> 6);
    const int lane = tid & 63;
    const float* w = Wp + (long)row * 1024;
    float s = 0.f;
    for (int j = lane; j < 1024; j += 64) s += w[j] * bv[j];
    for (int off = 32; off; off >>= 1) s += __shfl_down(s, off, 64);
    if (lane == 0) cv[row] = 2048.f * s + bp[row];
  }
}

// ---------------------------------------------------------------------
// reduce 4 split-K fp32 partial slabs -> bf16, *2048
__global__ void k_reduce(const float* __restrict__ p, u16* __restrict__ dst) {
  const long i = (long)(blockIdx.x * 256 + threadIdx.x) * 4;
  const float4 a = *(const float4*)(p + i);
  const float4 b = *(const float4*)(p + 1048576 + i);
  const float4 c = *(const float4*)(p + 2097152 + i);
  const float4 d = *(const float4*)(p + 3145728 + i);
  ushort4 o;
  o.x = f2bf((a.x + b.x + c.x + d.x) * 2048.f);
  o.y = f2bf((a.y + b.y + c.y + d.y) * 2048.f);
  o.z = f2bf((a.z + b.z + c.z + d.z) * 2048.f);
  o.w = f2bf((a.w + b.w + c.w + d.w) * 2048.f);
  *(ushort4*)(dst + i) = o;
}

// ---------------------------------------------------------------------
// NT bf16 GEMM: Out[M,N] (+bias) = A[M,K] @ B[N,K]^T
// BM=128, BN=128, BK=128. 256 threads = 4 waves (2x2), each 64x64
// (4x4 MFMA acc). Per K-iter: 64 MFMA/wave (307 cyc) per one vmcnt(0)
// drain -- amortizes the barrier-drain latency that capped R5/R6.
// LDS XOR-swizzled: 16B chunk kc of row r lives at slot kc ^ (r&7)
// (row = 256B = 16 chunks; XOR keeps chunks within their 8-group).
// MODE 0: fp32 out + bias, XCD-grouped 1-D grid. MODE 1: split-K slab.
template <int MODE>
__global__ __launch_bounds__(256, 2) void k_gemm(
    const u16* __restrict__ A, const u16* __restrict__ B, float* __restrict__ Out,
    const float* __restrict__ bias, int M, int N, int K) {
  __shared__ u16 As[128 * 128];  // 32 KB
  __shared__ u16 Bs[128 * 128];  // 32 KB

  const int tid = threadIdx.x;
  const int lane = tid & 63;
  const int wv = tid >> 6;
  const int waveM = (wv & 1) << 6;
  const int waveN = (wv >> 1) << 6;
  const int l15 = lane & 15;
  const int quad = lane >> 4;

  long bm, bn;
  int kBeg, kEnd;
  if constexpr (MODE == 0) {
    // XCD grouping: xcd = id&7 owns contiguous m-panels; a panel's
    // (N/128) n-blocks are temporally adjacent on that XCD.
    const int id = blockIdx.x;            // gridDim.x = (M/128)*(N/128)
    const int xcd = id & 7;
    const int j = id >> 3;
    const int nb = N >> 7;
    const int mPerXcd = M / 128 / 8;
    bm = (long)(xcd * mPerXcd + j / nb) * 128;
    bn = (long)(j % nb) * 128;
    kBeg = 0; kEnd = K;
  } else {
    bm = (long)blockIdx.x * 128;
    bn = (long)blockIdx.y * 128;
    const int kChunk = K / gridDim.z;
    kBeg = blockIdx.z * kChunk;
    kEnd = kBeg + kChunk;
  }

  // Staging: 8 calls each for A and B. Call r of wave wv fills the 1KB
  // LDS region at r*4096 + wv*1024 bytes = rows [r*16+wv*4, +4).
  // Lane l: row_local = l>>4, slot s = l&15, fetches global chunk
  // kc = s ^ (row&7)  (row&7 == rr&7, constant per thread).
  const int rr = (wv << 2) + (lane >> 4);   // 0..15
  const int s15 = lane & 15;
  const int kc = s15 ^ (rr & 7);
  const u16* Ag = A + (bm + rr) * (long)K + kc * 8;
  const u16* Bg = B + (bn + rr) * (long)K + kc * 8;
  u16* Asw = As + (wv << 9);
  u16* Bsw = Bs + (wv << 9);

  const f32x4 zero = {0.f, 0.f, 0.f, 0.f};
  f32x4 acc[4][4];
#pragma unroll
  for (int i = 0; i < 4; ++i)
#pragma unroll
    for (int j = 0; j < 4; ++j) acc[i][j] = zero;

  for (int k0 = kBeg; k0 < kEnd; k0 += 128) {
    __syncthreads();  // previous tile fully consumed
#pragma unroll
    for (int r = 0; r < 8; ++r)
      load16(Ag + (long)(r * 16) * K + k0, Asw + r * 2048);
#pragma unroll
    for (int r = 0; r < 8; ++r)
      load16(Bg + (long)(r * 16) * K + k0, Bsw + r * 2048);
    __syncthreads();  // staging drained (vmcnt(0) before s_barrier)

#pragma unroll
    for (int kk = 0; kk < 4; ++kk) {
      const int swz = ((kk << 2) + quad) ^ (l15 & 7);   // swizzled chunk
      bf16x8 af[4], bg[4];
#pragma unroll
      for (int t = 0; t < 4; ++t) {
        af[t] = *(const bf16x8*)(As + (waveM + t * 16 + l15) * 128 + swz * 8);
        bg[t] = *(const bf16x8*)(Bs + (waveN + t * 16 + l15) * 128 + swz * 8);
      }
#pragma unroll
      for (int i = 0; i < 4; ++i)
#pragma unroll
        for (int j = 0; j < 4; ++j)
          acc[i][j] = __builtin_amdgcn_mfma_f32_16x16x32_bf16(af[i], bg[j], acc[i][j], 0, 0, 0);
    }
  }

  // epilogue: C/D layout col = lane&15, row = quad*4 + reg  [m89/m91]
  float* outp = (MODE == 1) ? Out + (long)blockIdx.z * M * N : Out;
#pragma unroll
  for (int i = 0; i < 4; ++i) {
    const long gm = bm + waveM + i * 16 + quad * 4;
#pragma unroll
    for (int j = 0; j < 4; ++j) {
      const long gn = bn + waveN + j * 16 + l15;
      const float bb = (MODE == 0) ? bias[gn] : 0.f;
#pragma unroll
      for (int r = 0; r < 4; ++r)
        outp[(gm + r) * N + gn] = acc[i][j][r] + bb;
    }
  }
}

// =====================================================================
extern "C" void kernel_launch(void* const* d_in, const int* in_sizes, int n_in,
                              void* d_out, int out_size, void* d_ws, size_t ws_size,
                              hipStream_t stream) {
  // setup_inputs order: x, Wq, bq, Wk, bk, Wv, bv, Wp, bp
  const float* x  = (const float*)d_in[0];
  const float* Wv = (const float*)d_in[5];
  const float* bv = (const float*)d_in[6];
  const float* Wp = (const float*)d_in[7];
  const float* bp = (const float*)d_in[8];

  char* ws = (char*)d_ws;
  u16* xb    = (u16*)(ws);                      // 16 MB  x bf16
  u16* wpb   = (u16*)(ws + (16u << 20));        //  2 MB  Wp bf16
  u16* wvtb  = (u16*)(ws + (18u << 20));        //  2 MB  Wv^T bf16
  u16* m2b   = (u16*)(ws + (20u << 20));        //  2 MB  M2 bf16
  float* cv  = (float*)(ws + (22u << 20));      //  4 KB  folded bias
  float* m2f = (float*)(ws + (22u << 20) + 4096);  // 16 MB split-K partials

  // 1) fused prep: conv x / conv Wp / transpose Wv / bias fold
  k_prep<<<10496, 256, 0, stream>>>(x, Wv, bv, Wp, bp, xb, wpb, wvtb, cv);

  // 2) M2 partials = Wp @ Wv  (split-K=4: 8x8x4 = 256 blocks, 2 iters each)
  k_gemm<1><<<dim3(8, 8, 4), 256, 0, stream>>>(wpb, wvtb, m2f, nullptr,
                                               1024, 1024, 1024);
  // 3) M2 = bf16(2048 * sum of partials)
  k_reduce<<<1024, 256, 0, stream>>>(m2f, m2b);

  // 4) out = x @ M2^T + cv  (64 panels x 8 n-blocks = 512, XCD-grouped)
  k_gemm<0><<<512, 256, 0, stream>>>(xb, m2b, (float*)d_out, cv,
                                     8192, 1024, 1024);
}